// Round 4
// baseline (723.476 us; speedup 1.0000x reference)
//
#include <hip/hip_runtime.h>

#define N_NODES 100000
#define N_EDGES 1250000
#define D_FEAT  64

#define NPB       256                        // nodes per bin
#define NBINS     ((N_NODES + NPB - 1) / NPB)  // 391
#define SHARDS    8
#define SHARD_CAP 512                        // mean 400, +5.6 sigma
#define OVF_CAP   32768

// ---------------- primary: binned scatter + LDS-accumulated gather ----------------

// One atomic on a tiny L2-hot cursor array + one dense packed write per edge.
__global__ __launch_bounds__(256) void bin_scatter_kernel(
        const int* __restrict__ idxi, const int* __restrict__ idxj,
        int* __restrict__ cnt, int* __restrict__ ovfcnt,
        int* __restrict__ ovf, int* __restrict__ binbuf) {
    int e = blockIdx.x * blockDim.x + threadIdx.x;
    if (e >= N_EDGES) return;
    int d = idxi[e];
    int s = idxj[e];
    int bin   = d >> 8;           // 256 nodes per bin
    int dloc  = d & 255;
    int shard = e & (SHARDS - 1);
    int c = bin * SHARDS + shard;
    int pos = atomicAdd(&cnt[c], 1);
    if (pos < SHARD_CAP) {
        binbuf[(size_t)c * SHARD_CAP + pos] = (dloc << 17) | s;  // s < 2^17
    } else {
        int op = atomicAdd(ovfcnt, 1);
        if (op < OVF_CAP) { ovf[2 * op] = d; ovf[2 * op + 1] = s; }
    }
}

// One block per bin. 64KB LDS accumulator (256 rows x 64 feats).
// 16 waves: shard = wave>>1, two waves interleave within a shard.
__global__ __launch_bounds__(1024) void bin_gather_kernel(
        const float* __restrict__ x, const int* __restrict__ cnt,
        const int* __restrict__ binbuf, float* __restrict__ out) {
    __shared__ float acc[NPB * D_FEAT];      // 65536 B
    int tid = threadIdx.x;

    float4* a4 = (float4*)acc;
#pragma unroll
    for (int i = 0; i < 4; ++i)
        a4[tid + i * 1024] = make_float4(0.f, 0.f, 0.f, 0.f);
    __syncthreads();

    int bin  = blockIdx.x;
    int wave = tid >> 6;
    int lane = tid & 63;
    int shard = wave >> 1;                   // 0..7
    int ws    = wave & 1;
    int c = bin * SHARDS + shard;
    int len = cnt[c];
    if (len > SHARD_CAP) len = SHARD_CAP;
    const int* buf = binbuf + (size_t)c * SHARD_CAP;

    int k = ws;
    // 4-way unrolled for memory-level parallelism (independent row loads)
    for (; k + 6 < len; k += 8) {
        int p0 = buf[k];
        int p1 = buf[k + 2];
        int p2 = buf[k + 4];
        int p3 = buf[k + 6];
        float v0 = x[(size_t)(p0 & 0x1FFFF) * D_FEAT + lane];
        float v1 = x[(size_t)(p1 & 0x1FFFF) * D_FEAT + lane];
        float v2 = x[(size_t)(p2 & 0x1FFFF) * D_FEAT + lane];
        float v3 = x[(size_t)(p3 & 0x1FFFF) * D_FEAT + lane];
        atomicAdd(&acc[(p0 >> 17) * D_FEAT + lane], v0);
        atomicAdd(&acc[(p1 >> 17) * D_FEAT + lane], v1);
        atomicAdd(&acc[(p2 >> 17) * D_FEAT + lane], v2);
        atomicAdd(&acc[(p3 >> 17) * D_FEAT + lane], v3);
    }
    for (; k < len; k += 2) {
        int p = buf[k];
        float v = x[(size_t)(p & 0x1FFFF) * D_FEAT + lane];
        atomicAdd(&acc[(p >> 17) * D_FEAT + lane], v);
    }
    __syncthreads();

    // Coalesced float4 store of the bin's 256 rows.
    int base = bin * NPB;
#pragma unroll
    for (int i = 0; i < 4; ++i) {
        int f4  = tid + i * 1024;            // float4 index within bin
        int row = f4 >> 4;                   // 16 float4 per row
        int node = base + row;
        if (node < N_NODES)
            ((float4*)out)[(size_t)node * 16 + (f4 & 15)] = a4[f4];
    }
}

// Add any overflow edges (normally zero) on top of the gathered output.
__global__ __launch_bounds__(256) void ovf_fixup_kernel(
        const float* __restrict__ x, const int* __restrict__ ovfcnt,
        const int* __restrict__ ovf, float* __restrict__ out) {
    int n = *ovfcnt;
    if (n > OVF_CAP) n = OVF_CAP;
    long long total = (long long)n * 16;
    long long stride = (long long)gridDim.x * blockDim.x;
    for (long long t = blockIdx.x * blockDim.x + threadIdx.x; t < total; t += stride) {
        int e  = (int)(t >> 4);
        int fo = ((int)t & 15) << 2;
        int d = ovf[2 * e];
        int s = ovf[2 * e + 1];
        const float4 v = *(const float4*)(x + (size_t)s * D_FEAT + fo);
        float* o = out + (size_t)d * D_FEAT + fo;
        atomicAdd(o + 0, v.x);
        atomicAdd(o + 1, v.y);
        atomicAdd(o + 2, v.z);
        atomicAdd(o + 3, v.w);
    }
}

// ---------------- fallback: atomic scatter-add (needs no ws) ----------------

__global__ __launch_bounds__(256) void zero_f4_kernel(float* __restrict__ out, int n4) {
    int i = blockIdx.x * blockDim.x + threadIdx.x;
    if (i < n4) ((float4*)out)[i] = make_float4(0.f, 0.f, 0.f, 0.f);
}

__global__ __launch_bounds__(256) void scatter_add_kernel(const float* __restrict__ x,
                                                          const int* __restrict__ idxi,
                                                          const int* __restrict__ idxj,
                                                          float* __restrict__ out) {
    int t = blockIdx.x * blockDim.x + threadIdx.x;
    int e = t >> 4;
    if (e >= N_EDGES) return;
    int fo = (t & 15) << 2;
    int dst = idxi[e];
    int src = idxj[e];
    const float4 v = *(const float4*)(x + (size_t)src * D_FEAT + fo);
    float* o = out + (size_t)dst * D_FEAT + fo;
    atomicAdd(o + 0, v.x);
    atomicAdd(o + 1, v.y);
    atomicAdd(o + 2, v.z);
    atomicAdd(o + 3, v.w);
}

extern "C" void kernel_launch(void* const* d_in, const int* in_sizes, int n_in,
                              void* d_out, int out_size, void* d_ws, size_t ws_size,
                              hipStream_t stream) {
    const float* x  = (const float*)d_in[0];
    const int*   ei = (const int*)d_in[1];   // flat (2, N_EDGES)
    const int*   idxi = ei;                  // row 0: destinations
    const int*   idxj = ei + N_EDGES;        // row 1: sources
    float* out = (float*)d_out;

    int nbe = (N_EDGES + 255) / 256;         // 4883

    // ws (ints): cnt[NBINS*SHARDS] | ovfcnt+pad[16] | ovf[2*OVF_CAP] | binbuf[NBINS*SHARDS*SHARD_CAP]
    size_t n_cnt = (size_t)NBINS * SHARDS;
    size_t need = (n_cnt + 16 + 2 * (size_t)OVF_CAP +
                   (size_t)NBINS * SHARDS * SHARD_CAP) * sizeof(int);
    if (ws_size >= need) {
        int* cnt    = (int*)d_ws;
        int* ovfcnt = cnt + n_cnt;
        int* ovf    = ovfcnt + 16;
        int* binbuf = ovf + 2 * OVF_CAP;

        hipMemsetAsync(cnt, 0, (n_cnt + 16) * sizeof(int), stream);
        bin_scatter_kernel<<<nbe, 256, 0, stream>>>(idxi, idxj, cnt, ovfcnt, ovf, binbuf);
        bin_gather_kernel<<<NBINS, 1024, 0, stream>>>(x, cnt, binbuf, out);
        ovf_fixup_kernel<<<64, 256, 0, stream>>>(x, ovfcnt, ovf, out);
        return;
    }

    // fallback: plain atomic scatter-add
    int n4 = (N_NODES * D_FEAT) / 4;
    zero_f4_kernel<<<(n4 + 255) / 256, 256, 0, stream>>>(out, n4);
    long long total_threads = (long long)N_EDGES * 16;
    scatter_add_kernel<<<(int)((total_threads + 255) / 256), 256, 0, stream>>>(x, idxi, idxj, out);
}

// Round 5
// 220.216 us; speedup vs baseline: 3.2853x; 3.2853x over previous
//
#include <hip/hip_runtime.h>

#define N_NODES 100000
#define N_EDGES 1250000
#define D_FEAT  64

#define XSHARDS  8     // one shard per XCD (blockIdx % 8 round-robin)
#define SCAP     8     // slots per (node, shard): Poisson lambda=1.56, P(>8)~3e-5
#define OVF_CAP  32768

// fallback #1 (round-3) params
#define CAP      48
// ====================== primary: XCD-sharded buckets ======================

// One int atomic on cnt[node*8+xcd] + one dense-ish 4B write. All writes to a
// given 32B sub-bucket come from one XCD -> no cross-XCD line bouncing.
__global__ __launch_bounds__(256) void scatter_xcd_kernel(
        const int* __restrict__ idxi, const int* __restrict__ idxj,
        int* __restrict__ cnt, int* __restrict__ ovfcnt,
        int* __restrict__ ovf, int* __restrict__ bucket) {
    int e = blockIdx.x * blockDim.x + threadIdx.x;
    if (e >= N_EDGES) return;
    int d = idxi[e];
    int s = idxj[e];
    int shard = blockIdx.x & (XSHARDS - 1);          // == this block's XCD
    int c = atomicAdd(&cnt[d * XSHARDS + shard], 1);
    if (c < SCAP) {
        bucket[(size_t)d * (XSHARDS * SCAP) + shard * SCAP + c] = s;
    } else {
        int op = atomicAdd(ovfcnt, 1);
        if (op < OVF_CAP) { ovf[2 * op] = d; ovf[2 * op + 1] = s; }
    }
}

// One wave per node, lane = feature. One coalesced 256B load grabs the node's
// whole 64-slot bucket (one int per lane); ballot-compact valid slots into a
// per-wave LDS list; then 4-way-MLP gather of x rows, register accumulate.
__global__ __launch_bounds__(256) void gather_xcd_kernel(
        const float* __restrict__ x, const int* __restrict__ cnt,
        const int* __restrict__ bucket, float* __restrict__ out) {
    __shared__ int list_s[4 * 64];
    int tid  = threadIdx.x;
    int node = blockIdx.x * 4 + (tid >> 6);
    int lane = tid & 63;
    if (node >= N_NODES) return;

    // shard counts: lane l<8 holds cnt of shard l
    int cs = 0;
    if (lane < 8) {
        cs = cnt[node * XSHARDS + lane];
        if (cs > SCAP) cs = SCAP;
    }
    int myshard_cnt = __shfl(cs, lane >> 3, 64);     // count of the shard my slot is in

    // whole bucket row: 64 ints, coalesced 256B
    int slot = bucket[(size_t)node * (XSHARDS * SCAP) + lane];
    bool valid = (lane & (SCAP - 1)) < myshard_cnt;

    unsigned long long mask = __ballot(valid);
    int tot = __popcll(mask);
    int pre = __popcll(mask & ((1ULL << lane) - 1ULL));
    int* list = list_s + (tid >> 6) * 64;
    if (valid) list[pre] = slot;
    // ds_write -> ds_read within the same wave: compiler inserts lgkmcnt wait.

    float acc = 0.f;
    int k = 0;
    for (; k + 4 <= tot; k += 4) {
        int s0 = list[k], s1 = list[k + 1], s2 = list[k + 2], s3 = list[k + 3];
        float a0 = x[(size_t)s0 * D_FEAT + lane];
        float a1 = x[(size_t)s1 * D_FEAT + lane];
        float a2 = x[(size_t)s2 * D_FEAT + lane];
        float a3 = x[(size_t)s3 * D_FEAT + lane];
        acc += (a0 + a1) + (a2 + a3);
    }
    for (; k < tot; ++k) acc += x[(size_t)list[k] * D_FEAT + lane];

    out[(size_t)node * D_FEAT + lane] = acc;
}

// Add any overflow edges (statistically ~30) on top of the gathered output.
__global__ __launch_bounds__(256) void ovf_fixup_kernel(
        const float* __restrict__ x, const int* __restrict__ ovfcnt,
        const int* __restrict__ ovf, float* __restrict__ out) {
    int n = *ovfcnt;
    if (n > OVF_CAP) n = OVF_CAP;
    long long total = (long long)n * 16;
    long long stride = (long long)gridDim.x * blockDim.x;
    for (long long t = blockIdx.x * blockDim.x + threadIdx.x; t < total; t += stride) {
        int e  = (int)(t >> 4);
        int fo = ((int)t & 15) << 2;
        int d = ovf[2 * e];
        int s = ovf[2 * e + 1];
        const float4 v = *(const float4*)(x + (size_t)s * D_FEAT + fo);
        float* o = out + (size_t)d * D_FEAT + fo;
        atomicAdd(o + 0, v.x);
        atomicAdd(o + 1, v.y);
        atomicAdd(o + 2, v.z);
        atomicAdd(o + 3, v.w);
    }
}

// ====================== fallback #1: round-3 padded buckets ======================

__global__ __launch_bounds__(256) void scatter_pad_kernel(
        const int* __restrict__ idxi, const int* __restrict__ idxj,
        int* __restrict__ cnt, int* __restrict__ ovfcnt,
        int* __restrict__ ovf, int* __restrict__ bucket) {
    int e = blockIdx.x * blockDim.x + threadIdx.x;
    if (e >= N_EDGES) return;
    int d = idxi[e];
    int s = idxj[e];
    int pos = atomicAdd(&cnt[d], 1);
    if (pos < CAP) {
        bucket[(size_t)d * CAP + pos] = s;
    } else {
        int op = atomicAdd(ovfcnt, 1);
        if (op < OVF_CAP) { ovf[2 * op] = d; ovf[2 * op + 1] = s; }
    }
}

__global__ __launch_bounds__(256) void gather_pad_kernel(
        const float* __restrict__ x, const int* __restrict__ cnt,
        const int* __restrict__ bucket, float* __restrict__ out) {
    int node = blockIdx.x * 4 + (threadIdx.x >> 6);
    int lane = threadIdx.x & 63;
    if (node >= N_NODES) return;
    int c = cnt[node];
    if (c > CAP) c = CAP;
    const int* b = bucket + (size_t)node * CAP;
    float acc = 0.f;
    int k = 0;
    for (; k + 4 <= c; k += 4) {
        int4 s4 = *(const int4*)(b + k);
        float a0 = x[(size_t)s4.x * D_FEAT + lane];
        float a1 = x[(size_t)s4.y * D_FEAT + lane];
        float a2 = x[(size_t)s4.z * D_FEAT + lane];
        float a3 = x[(size_t)s4.w * D_FEAT + lane];
        acc += (a0 + a1) + (a2 + a3);
    }
    for (; k < c; ++k) acc += x[(size_t)b[k] * D_FEAT + lane];
    out[(size_t)node * D_FEAT + lane] = acc;
}

// ====================== fallback #2: atomic scatter-add ======================

__global__ __launch_bounds__(256) void zero_f4_kernel(float* __restrict__ out, int n4) {
    int i = blockIdx.x * blockDim.x + threadIdx.x;
    if (i < n4) ((float4*)out)[i] = make_float4(0.f, 0.f, 0.f, 0.f);
}

__global__ __launch_bounds__(256) void scatter_add_kernel(const float* __restrict__ x,
                                                          const int* __restrict__ idxi,
                                                          const int* __restrict__ idxj,
                                                          float* __restrict__ out) {
    int t = blockIdx.x * blockDim.x + threadIdx.x;
    int e = t >> 4;
    if (e >= N_EDGES) return;
    int fo = (t & 15) << 2;
    int dst = idxi[e];
    int src = idxj[e];
    const float4 v = *(const float4*)(x + (size_t)src * D_FEAT + fo);
    float* o = out + (size_t)dst * D_FEAT + fo;
    atomicAdd(o + 0, v.x);
    atomicAdd(o + 1, v.y);
    atomicAdd(o + 2, v.z);
    atomicAdd(o + 3, v.w);
}

extern "C" void kernel_launch(void* const* d_in, const int* in_sizes, int n_in,
                              void* d_out, int out_size, void* d_ws, size_t ws_size,
                              hipStream_t stream) {
    const float* x  = (const float*)d_in[0];
    const int*   ei = (const int*)d_in[1];   // flat (2, N_EDGES)
    const int*   idxi = ei;                  // row 0: destinations
    const int*   idxj = ei + N_EDGES;        // row 1: sources
    float* out = (float*)d_out;

    int nbe = (N_EDGES + 255) / 256;         // 4883
    int gather_blocks = (N_NODES + 3) / 4;   // 25000

    // --- primary: XCD-sharded buckets ---
    // ws (ints): cnt[N_NODES*8] | ovfcnt+pad[16] | ovf[2*OVF_CAP] | bucket[N_NODES*64]
    {
        size_t n_cnt = (size_t)N_NODES * XSHARDS;
        size_t need = (n_cnt + 16 + 2 * (size_t)OVF_CAP +
                       (size_t)N_NODES * XSHARDS * SCAP) * sizeof(int);
        if (ws_size >= need) {
            int* cnt    = (int*)d_ws;
            int* ovfcnt = cnt + n_cnt;
            int* ovf    = ovfcnt + 16;
            int* bucket = ovf + 2 * OVF_CAP;

            hipMemsetAsync(cnt, 0, (n_cnt + 16) * sizeof(int), stream);
            scatter_xcd_kernel<<<nbe, 256, 0, stream>>>(idxi, idxj, cnt, ovfcnt, ovf, bucket);
            gather_xcd_kernel<<<gather_blocks, 256, 0, stream>>>(x, cnt, bucket, out);
            ovf_fixup_kernel<<<64, 256, 0, stream>>>(x, ovfcnt, ovf, out);
            return;
        }
    }

    // --- fallback #1: round-3 padded buckets ---
    {
        size_t need = ((size_t)N_NODES + 16 + 2 * (size_t)OVF_CAP +
                       (size_t)N_NODES * CAP) * sizeof(int);
        if (ws_size >= need) {
            int* cnt    = (int*)d_ws;
            int* ovfcnt = cnt + N_NODES;
            int* ovf    = cnt + N_NODES + 16;
            int* bucket = ovf + 2 * OVF_CAP;

            hipMemsetAsync(cnt, 0, (N_NODES + 16) * sizeof(int), stream);
            scatter_pad_kernel<<<nbe, 256, 0, stream>>>(idxi, idxj, cnt, ovfcnt, ovf, bucket);
            gather_pad_kernel<<<gather_blocks, 256, 0, stream>>>(x, cnt, bucket, out);
            ovf_fixup_kernel<<<64, 256, 0, stream>>>(x, ovfcnt, ovf, out);
            return;
        }
    }

    // --- fallback #2: atomic scatter-add ---
    int n4 = (N_NODES * D_FEAT) / 4;
    zero_f4_kernel<<<(n4 + 255) / 256, 256, 0, stream>>>(out, n4);
    long long total_threads = (long long)N_EDGES * 16;
    scatter_add_kernel<<<(int)((total_threads + 255) / 256), 256, 0, stream>>>(x, idxi, idxj, out);
}

// Round 6
// 159.434 us; speedup vs baseline: 4.5378x; 1.3812x over previous
//
#include <hip/hip_runtime.h>

#define N_NODES 100000
#define N_EDGES 1250000
#define D_FEAT  64

#define NPB     256                          // nodes per bin
#define NBINS   ((N_NODES + NPB - 1) / NPB)  // 391
#define BCAP    4096                         // entries per bin (mean 3196, +16 sigma)
#define EPB     8192                         // edges per k1 block
#define K1B     ((N_EDGES + EPB - 1) / EPB)  // 153
#define OVF_CAP 32768

#define CAP     48                           // fallback #1 per-node bucket cap

// =============== primary: LDS-staged counting sort + CSR gather ===============

// Coarse binning: per-block LDS histogram over 391 bins, bulk cursor
// reservation, dense run writes of packed (dloc<<17 | src).
__global__ __launch_bounds__(1024) void k1_bin_kernel(
        const int* __restrict__ idxi, const int* __restrict__ idxj,
        int* __restrict__ gcursor, int* __restrict__ ovfcnt,
        int* __restrict__ ovf, int* __restrict__ binbuf) {
    __shared__ int hist[NBINS];
    __shared__ int cur[NBINS];
    __shared__ int gbase[NBINS];
    int t = threadIdx.x;
    for (int i = t; i < NBINS; i += 1024) hist[i] = 0;
    __syncthreads();

    long long base = (long long)blockIdx.x * EPB;
    int d[8], s[8], bn[8];
#pragma unroll
    for (int j = 0; j < 8; ++j) {
        long long e = base + t + j * 1024;
        if (e < N_EDGES) {
            d[j] = idxi[e];
            s[j] = idxj[e];
            bn[j] = d[j] >> 8;
            atomicAdd(&hist[bn[j]], 1);
        } else {
            bn[j] = -1;
        }
    }
    __syncthreads();

    for (int i = t; i < NBINS; i += 1024) {
        int h = hist[i];
        gbase[i] = h ? atomicAdd(&gcursor[i], h) : 0;
        cur[i] = 0;
    }
    __syncthreads();

#pragma unroll
    for (int j = 0; j < 8; ++j) {
        if (bn[j] >= 0) {
            int lofs = atomicAdd(&cur[bn[j]], 1);
            int idx = gbase[bn[j]] + lofs;
            if (idx < BCAP) {
                binbuf[(size_t)bn[j] * BCAP + idx] = ((d[j] & 255) << 17) | s[j];
            } else {
                int op = atomicAdd(ovfcnt, 1);
                if (op < OVF_CAP) { ovf[2 * op] = d[j]; ovf[2 * op + 1] = s[j]; }
            }
        }
    }
}

// Per-bin counting sort by local node id -> per-node CSR lists + offs/len.
__global__ __launch_bounds__(1024) void k2_sort_kernel(
        const int* __restrict__ gcursor, const int* __restrict__ binbuf,
        int* __restrict__ sorted, int* __restrict__ offs, int* __restrict__ len) {
    __shared__ int cnt[NPB];
    __shared__ int excl[NPB];
    __shared__ int cur[NPB];
    __shared__ int stmp[NPB];
    int bin = blockIdx.x;
    int t = threadIdx.x;
    if (t < NPB) cnt[t] = 0;
    __syncthreads();

    int n = gcursor[bin];
    if (n > BCAP) n = BCAP;
    const int* src = binbuf + (size_t)bin * BCAP;
    int p[4];
#pragma unroll
    for (int j = 0; j < 4; ++j) {
        int i = t + j * 1024;
        p[j] = (i < n) ? src[i] : -1;
        if (p[j] >= 0) atomicAdd(&cnt[p[j] >> 17], 1);
    }
    __syncthreads();

    // exclusive scan of cnt[256]
    if (t < NPB) stmp[t] = cnt[t];
    __syncthreads();
    for (int off = 1; off < NPB; off <<= 1) {
        int v = 0;
        if (t < NPB && t >= off) v = stmp[t - off];
        __syncthreads();
        if (t < NPB) stmp[t] += v;
        __syncthreads();
    }
    if (t < NPB) {
        excl[t] = stmp[t] - cnt[t];
        cur[t] = 0;
        int node = bin * NPB + t;
        if (node < N_NODES) {
            offs[node] = bin * BCAP + excl[t];
            len[node]  = cnt[t];
        }
    }
    __syncthreads();

    int* dst = sorted + (size_t)bin * BCAP;
#pragma unroll
    for (int j = 0; j < 4; ++j) {
        if (p[j] >= 0) {
            int dl = p[j] >> 17;
            int pos = excl[dl] + atomicAdd(&cur[dl], 1);
            dst[pos] = p[j] & 0x1FFFF;
        }
    }
}

// One wave per node, lane = feature; 4-way MLP, register accumulate.
__global__ __launch_bounds__(256) void k3_gather_kernel(
        const float* __restrict__ x, const int* __restrict__ offs,
        const int* __restrict__ len, const int* __restrict__ sorted,
        float* __restrict__ out) {
    int node = blockIdx.x * 4 + (threadIdx.x >> 6);
    int lane = threadIdx.x & 63;
    if (node >= N_NODES) return;
    const int* b = sorted + offs[node];
    int l = len[node];
    float acc = 0.f;
    int k = 0;
    for (; k + 4 <= l; k += 4) {
        int s0 = b[k], s1 = b[k + 1], s2 = b[k + 2], s3 = b[k + 3];
        float a0 = x[(size_t)s0 * D_FEAT + lane];
        float a1 = x[(size_t)s1 * D_FEAT + lane];
        float a2 = x[(size_t)s2 * D_FEAT + lane];
        float a3 = x[(size_t)s3 * D_FEAT + lane];
        acc += (a0 + a1) + (a2 + a3);
    }
    for (; k < l; ++k) acc += x[(size_t)b[k] * D_FEAT + lane];
    out[(size_t)node * D_FEAT + lane] = acc;
}

// Add any overflow edges (statistically none) on top of the gathered output.
__global__ __launch_bounds__(256) void ovf_fixup_kernel(
        const float* __restrict__ x, const int* __restrict__ ovfcnt,
        const int* __restrict__ ovf, float* __restrict__ out) {
    int n = *ovfcnt;
    if (n > OVF_CAP) n = OVF_CAP;
    long long total = (long long)n * 16;
    long long stride = (long long)gridDim.x * blockDim.x;
    for (long long t = blockIdx.x * blockDim.x + threadIdx.x; t < total; t += stride) {
        int e  = (int)(t >> 4);
        int fo = ((int)t & 15) << 2;
        int d = ovf[2 * e];
        int s = ovf[2 * e + 1];
        const float4 v = *(const float4*)(x + (size_t)s * D_FEAT + fo);
        float* o = out + (size_t)d * D_FEAT + fo;
        atomicAdd(o + 0, v.x);
        atomicAdd(o + 1, v.y);
        atomicAdd(o + 2, v.z);
        atomicAdd(o + 3, v.w);
    }
}

// ====================== fallback #1: round-3 padded buckets ======================

__global__ __launch_bounds__(256) void scatter_pad_kernel(
        const int* __restrict__ idxi, const int* __restrict__ idxj,
        int* __restrict__ cnt, int* __restrict__ ovfcnt,
        int* __restrict__ ovf, int* __restrict__ bucket) {
    int e = blockIdx.x * blockDim.x + threadIdx.x;
    if (e >= N_EDGES) return;
    int d = idxi[e];
    int s = idxj[e];
    int pos = atomicAdd(&cnt[d], 1);
    if (pos < CAP) {
        bucket[(size_t)d * CAP + pos] = s;
    } else {
        int op = atomicAdd(ovfcnt, 1);
        if (op < OVF_CAP) { ovf[2 * op] = d; ovf[2 * op + 1] = s; }
    }
}

__global__ __launch_bounds__(256) void gather_pad_kernel(
        const float* __restrict__ x, const int* __restrict__ cnt,
        const int* __restrict__ bucket, float* __restrict__ out) {
    int node = blockIdx.x * 4 + (threadIdx.x >> 6);
    int lane = threadIdx.x & 63;
    if (node >= N_NODES) return;
    int c = cnt[node];
    if (c > CAP) c = CAP;
    const int* b = bucket + (size_t)node * CAP;
    float acc = 0.f;
    int k = 0;
    for (; k + 4 <= c; k += 4) {
        int4 s4 = *(const int4*)(b + k);
        float a0 = x[(size_t)s4.x * D_FEAT + lane];
        float a1 = x[(size_t)s4.y * D_FEAT + lane];
        float a2 = x[(size_t)s4.z * D_FEAT + lane];
        float a3 = x[(size_t)s4.w * D_FEAT + lane];
        acc += (a0 + a1) + (a2 + a3);
    }
    for (; k < c; ++k) acc += x[(size_t)b[k] * D_FEAT + lane];
    out[(size_t)node * D_FEAT + lane] = acc;
}

// ====================== fallback #2: atomic scatter-add ======================

__global__ __launch_bounds__(256) void zero_f4_kernel(float* __restrict__ out, int n4) {
    int i = blockIdx.x * blockDim.x + threadIdx.x;
    if (i < n4) ((float4*)out)[i] = make_float4(0.f, 0.f, 0.f, 0.f);
}

__global__ __launch_bounds__(256) void scatter_add_kernel(const float* __restrict__ x,
                                                          const int* __restrict__ idxi,
                                                          const int* __restrict__ idxj,
                                                          float* __restrict__ out) {
    int t = blockIdx.x * blockDim.x + threadIdx.x;
    int e = t >> 4;
    if (e >= N_EDGES) return;
    int fo = (t & 15) << 2;
    int dst = idxi[e];
    int src = idxj[e];
    const float4 v = *(const float4*)(x + (size_t)src * D_FEAT + fo);
    float* o = out + (size_t)dst * D_FEAT + fo;
    atomicAdd(o + 0, v.x);
    atomicAdd(o + 1, v.y);
    atomicAdd(o + 2, v.z);
    atomicAdd(o + 3, v.w);
}

extern "C" void kernel_launch(void* const* d_in, const int* in_sizes, int n_in,
                              void* d_out, int out_size, void* d_ws, size_t ws_size,
                              hipStream_t stream) {
    const float* x  = (const float*)d_in[0];
    const int*   ei = (const int*)d_in[1];   // flat (2, N_EDGES)
    const int*   idxi = ei;                  // row 0: destinations
    const int*   idxj = ei + N_EDGES;        // row 1: sources
    float* out = (float*)d_out;

    int nbe = (N_EDGES + 255) / 256;         // 4883
    int gather_blocks = (N_NODES + 3) / 4;   // 25000

    // --- primary: counting-sort CSR ---
    // ws (ints): gcursor[512] | ovfcnt+pad[16] | ovf[2*OVF_CAP] |
    //            binbuf[NBINS*BCAP] | sorted[NBINS*BCAP] | offs[N_NODES] | len[N_NODES]
    {
        size_t need = (512 + 16 + 2 * (size_t)OVF_CAP +
                       2 * (size_t)NBINS * BCAP + 2 * (size_t)N_NODES) * sizeof(int);
        if (ws_size >= need) {
            int* gcursor = (int*)d_ws;
            int* ovfcnt  = gcursor + 512;
            int* ovf     = ovfcnt + 16;
            int* binbuf  = ovf + 2 * OVF_CAP;
            int* sorted  = binbuf + (size_t)NBINS * BCAP;
            int* offs    = sorted + (size_t)NBINS * BCAP;
            int* len     = offs + N_NODES;

            hipMemsetAsync(gcursor, 0, (512 + 16) * sizeof(int), stream);
            k1_bin_kernel<<<K1B, 1024, 0, stream>>>(idxi, idxj, gcursor, ovfcnt, ovf, binbuf);
            k2_sort_kernel<<<NBINS, 1024, 0, stream>>>(gcursor, binbuf, sorted, offs, len);
            k3_gather_kernel<<<gather_blocks, 256, 0, stream>>>(x, offs, len, sorted, out);
            ovf_fixup_kernel<<<64, 256, 0, stream>>>(x, ovfcnt, ovf, out);
            return;
        }
    }

    // --- fallback #1: round-3 padded buckets ---
    {
        size_t need = ((size_t)N_NODES + 16 + 2 * (size_t)OVF_CAP +
                       (size_t)N_NODES * CAP) * sizeof(int);
        if (ws_size >= need) {
            int* cnt    = (int*)d_ws;
            int* ovfcnt = cnt + N_NODES;
            int* ovf    = cnt + N_NODES + 16;
            int* bucket = ovf + 2 * OVF_CAP;

            hipMemsetAsync(cnt, 0, (N_NODES + 16) * sizeof(int), stream);
            scatter_pad_kernel<<<nbe, 256, 0, stream>>>(idxi, idxj, cnt, ovfcnt, ovf, bucket);
            gather_pad_kernel<<<gather_blocks, 256, 0, stream>>>(x, cnt, bucket, out);
            ovf_fixup_kernel<<<64, 256, 0, stream>>>(x, ovfcnt, ovf, out);
            return;
        }
    }

    // --- fallback #2: atomic scatter-add ---
    int n4 = (N_NODES * D_FEAT) / 4;
    zero_f4_kernel<<<(n4 + 255) / 256, 256, 0, stream>>>(out, n4);
    long long total_threads = (long long)N_EDGES * 16;
    scatter_add_kernel<<<(int)((total_threads + 255) / 256), 256, 0, stream>>>(x, idxi, idxj, out);
}

// Round 7
// 149.918 us; speedup vs baseline: 4.8258x; 1.0635x over previous
//
#include <hip/hip_runtime.h>

#define N_NODES 100000
#define N_EDGES 1250000
#define D_FEAT  64

#define NPB     256                          // nodes per bin
#define NBINS   ((N_NODES + NPB - 1) / NPB)  // 391
#define BCAP    4096                         // entries per bin (mean 3196, +16 sigma)
#define EPB     4096                         // edges per k1 block
#define K1B     ((N_EDGES + EPB - 1) / EPB)  // 306
#define OVF_CAP 32768

#define CAP     48                           // fallback #1 per-node bucket cap

// =============== primary: LDS-staged counting sort + CSR gather ===============

// Coarse binning: per-block LDS histogram over 391 bins, bulk cursor
// reservation, dense run writes of packed (dloc<<17 | src).
__global__ __launch_bounds__(512) void k1_bin_kernel(
        const int* __restrict__ idxi, const int* __restrict__ idxj,
        int* __restrict__ gcursor, int* __restrict__ ovfcnt,
        int* __restrict__ ovf, int* __restrict__ binbuf) {
    __shared__ int hist[NBINS];
    __shared__ int cur[NBINS];
    __shared__ int gbase[NBINS];
    int t = threadIdx.x;
    for (int i = t; i < NBINS; i += 512) hist[i] = 0;
    __syncthreads();

    long long base = (long long)blockIdx.x * EPB;
    int d[8], s[8], bn[8];
#pragma unroll
    for (int j = 0; j < 8; ++j) {
        long long e = base + t + j * 512;
        if (e < N_EDGES) {
            d[j] = idxi[e];
            s[j] = idxj[e];
            bn[j] = d[j] >> 8;
            atomicAdd(&hist[bn[j]], 1);
        } else {
            bn[j] = -1;
        }
    }
    __syncthreads();

    for (int i = t; i < NBINS; i += 512) {
        int h = hist[i];
        gbase[i] = h ? atomicAdd(&gcursor[i], h) : 0;
        cur[i] = 0;
    }
    __syncthreads();

#pragma unroll
    for (int j = 0; j < 8; ++j) {
        if (bn[j] >= 0) {
            int lofs = atomicAdd(&cur[bn[j]], 1);
            int idx = gbase[bn[j]] + lofs;
            if (idx < BCAP) {
                binbuf[(size_t)bn[j] * BCAP + idx] = ((d[j] & 255) << 17) | s[j];
            } else {
                int op = atomicAdd(ovfcnt, 1);
                if (op < OVF_CAP) { ovf[2 * op] = d[j]; ovf[2 * op + 1] = s[j]; }
            }
        }
    }
}

// Per-bin counting sort by local node id -> per-node CSR lists + offs/len.
__global__ __launch_bounds__(1024) void k2_sort_kernel(
        const int* __restrict__ gcursor, const int* __restrict__ binbuf,
        int* __restrict__ sorted, int* __restrict__ offs, int* __restrict__ len) {
    __shared__ int cnt[NPB];
    __shared__ int excl[NPB];
    __shared__ int cur[NPB];
    __shared__ int stmp[NPB];
    int bin = blockIdx.x;
    int t = threadIdx.x;
    if (t < NPB) cnt[t] = 0;
    __syncthreads();

    int n = gcursor[bin];
    if (n > BCAP) n = BCAP;
    const int* src = binbuf + (size_t)bin * BCAP;
    int p[4];
#pragma unroll
    for (int j = 0; j < 4; ++j) {
        int i = t + j * 1024;
        p[j] = (i < n) ? src[i] : -1;
        if (p[j] >= 0) atomicAdd(&cnt[p[j] >> 17], 1);
    }
    __syncthreads();

    // exclusive scan of cnt[256]
    if (t < NPB) stmp[t] = cnt[t];
    __syncthreads();
    for (int off = 1; off < NPB; off <<= 1) {
        int v = 0;
        if (t < NPB && t >= off) v = stmp[t - off];
        __syncthreads();
        if (t < NPB) stmp[t] += v;
        __syncthreads();
    }
    if (t < NPB) {
        excl[t] = stmp[t] - cnt[t];
        cur[t] = 0;
        int node = bin * NPB + t;
        if (node < N_NODES) {
            offs[node] = bin * BCAP + excl[t];
            len[node]  = cnt[t];
        }
    }
    __syncthreads();

    int* dst = sorted + (size_t)bin * BCAP;
#pragma unroll
    for (int j = 0; j < 4; ++j) {
        if (p[j] >= 0) {
            int dl = p[j] >> 17;
            int pos = excl[dl] + atomicAdd(&cur[dl], 1);
            dst[pos] = p[j] & 0x1FFFF;
        }
    }
}

// One wave per node; lanes = 4 sub-rows x 16 float4-columns. Each float4 load
// instruction covers 4 rows (1KB/wave); 2x unroll -> 8 rows in flight.
__global__ __launch_bounds__(256) void k3_gather_kernel(
        const float* __restrict__ x, const int* __restrict__ offs,
        const int* __restrict__ len, const int* __restrict__ sorted,
        float* __restrict__ out) {
    int node = blockIdx.x * 4 + (threadIdx.x >> 6);
    int lane = threadIdx.x & 63;
    if (node >= N_NODES) return;
    const int* b = sorted + offs[node];
    int l = len[node];
    int sub = lane >> 4;          // which row within a group of 4
    int c4  = lane & 15;          // which float4 column

    float4 acc = make_float4(0.f, 0.f, 0.f, 0.f);
    int k = 0;
    for (; k + 8 <= l; k += 8) {
        int s0 = b[k + sub];
        int s1 = b[k + 4 + sub];
        const float4 v0 = *(const float4*)(x + (size_t)s0 * D_FEAT + c4 * 4);
        const float4 v1 = *(const float4*)(x + (size_t)s1 * D_FEAT + c4 * 4);
        acc.x += v0.x + v1.x;
        acc.y += v0.y + v1.y;
        acc.z += v0.z + v1.z;
        acc.w += v0.w + v1.w;
    }
    if (k + 4 <= l) {
        int s0 = b[k + sub];
        const float4 v0 = *(const float4*)(x + (size_t)s0 * D_FEAT + c4 * 4);
        acc.x += v0.x; acc.y += v0.y; acc.z += v0.z; acc.w += v0.w;
        k += 4;
    }
    if (k + sub < l) {
        int s0 = b[k + sub];
        const float4 v0 = *(const float4*)(x + (size_t)s0 * D_FEAT + c4 * 4);
        acc.x += v0.x; acc.y += v0.y; acc.z += v0.z; acc.w += v0.w;
    }

    // fold the 4 sub-row partials: lanes differing in bits 4,5 hold the same c4
    acc.x += __shfl_xor(acc.x, 16, 64);
    acc.y += __shfl_xor(acc.y, 16, 64);
    acc.z += __shfl_xor(acc.z, 16, 64);
    acc.w += __shfl_xor(acc.w, 16, 64);
    acc.x += __shfl_xor(acc.x, 32, 64);
    acc.y += __shfl_xor(acc.y, 32, 64);
    acc.z += __shfl_xor(acc.z, 32, 64);
    acc.w += __shfl_xor(acc.w, 32, 64);

    if (sub == 0 && (lane >> 4) == 0) {   // lanes 0..15
        ((float4*)out)[(size_t)node * 16 + c4] = acc;
    }
}

// Add any overflow edges (statistically none) on top of the gathered output.
__global__ __launch_bounds__(256) void ovf_fixup_kernel(
        const float* __restrict__ x, const int* __restrict__ ovfcnt,
        const int* __restrict__ ovf, float* __restrict__ out) {
    int n = *ovfcnt;
    if (n > OVF_CAP) n = OVF_CAP;
    long long total = (long long)n * 16;
    long long stride = (long long)gridDim.x * blockDim.x;
    for (long long t = blockIdx.x * blockDim.x + threadIdx.x; t < total; t += stride) {
        int e  = (int)(t >> 4);
        int fo = ((int)t & 15) << 2;
        int d = ovf[2 * e];
        int s = ovf[2 * e + 1];
        const float4 v = *(const float4*)(x + (size_t)s * D_FEAT + fo);
        float* o = out + (size_t)d * D_FEAT + fo;
        atomicAdd(o + 0, v.x);
        atomicAdd(o + 1, v.y);
        atomicAdd(o + 2, v.z);
        atomicAdd(o + 3, v.w);
    }
}

// ====================== fallback #1: round-3 padded buckets ======================

__global__ __launch_bounds__(256) void scatter_pad_kernel(
        const int* __restrict__ idxi, const int* __restrict__ idxj,
        int* __restrict__ cnt, int* __restrict__ ovfcnt,
        int* __restrict__ ovf, int* __restrict__ bucket) {
    int e = blockIdx.x * blockDim.x + threadIdx.x;
    if (e >= N_EDGES) return;
    int d = idxi[e];
    int s = idxj[e];
    int pos = atomicAdd(&cnt[d], 1);
    if (pos < CAP) {
        bucket[(size_t)d * CAP + pos] = s;
    } else {
        int op = atomicAdd(ovfcnt, 1);
        if (op < OVF_CAP) { ovf[2 * op] = d; ovf[2 * op + 1] = s; }
    }
}

__global__ __launch_bounds__(256) void gather_pad_kernel(
        const float* __restrict__ x, const int* __restrict__ cnt,
        const int* __restrict__ bucket, float* __restrict__ out) {
    int node = blockIdx.x * 4 + (threadIdx.x >> 6);
    int lane = threadIdx.x & 63;
    if (node >= N_NODES) return;
    int c = cnt[node];
    if (c > CAP) c = CAP;
    const int* b = bucket + (size_t)node * CAP;
    float acc = 0.f;
    int k = 0;
    for (; k + 4 <= c; k += 4) {
        int4 s4 = *(const int4*)(b + k);
        float a0 = x[(size_t)s4.x * D_FEAT + lane];
        float a1 = x[(size_t)s4.y * D_FEAT + lane];
        float a2 = x[(size_t)s4.z * D_FEAT + lane];
        float a3 = x[(size_t)s4.w * D_FEAT + lane];
        acc += (a0 + a1) + (a2 + a3);
    }
    for (; k < c; ++k) acc += x[(size_t)b[k] * D_FEAT + lane];
    out[(size_t)node * D_FEAT + lane] = acc;
}

// ====================== fallback #2: atomic scatter-add ======================

__global__ __launch_bounds__(256) void zero_f4_kernel(float* __restrict__ out, int n4) {
    int i = blockIdx.x * blockDim.x + threadIdx.x;
    if (i < n4) ((float4*)out)[i] = make_float4(0.f, 0.f, 0.f, 0.f);
}

__global__ __launch_bounds__(256) void scatter_add_kernel(const float* __restrict__ x,
                                                          const int* __restrict__ idxi,
                                                          const int* __restrict__ idxj,
                                                          float* __restrict__ out) {
    int t = blockIdx.x * blockDim.x + threadIdx.x;
    int e = t >> 4;
    if (e >= N_EDGES) return;
    int fo = (t & 15) << 2;
    int dst = idxi[e];
    int src = idxj[e];
    const float4 v = *(const float4*)(x + (size_t)src * D_FEAT + fo);
    float* o = out + (size_t)dst * D_FEAT + fo;
    atomicAdd(o + 0, v.x);
    atomicAdd(o + 1, v.y);
    atomicAdd(o + 2, v.z);
    atomicAdd(o + 3, v.w);
}

extern "C" void kernel_launch(void* const* d_in, const int* in_sizes, int n_in,
                              void* d_out, int out_size, void* d_ws, size_t ws_size,
                              hipStream_t stream) {
    const float* x  = (const float*)d_in[0];
    const int*   ei = (const int*)d_in[1];   // flat (2, N_EDGES)
    const int*   idxi = ei;                  // row 0: destinations
    const int*   idxj = ei + N_EDGES;        // row 1: sources
    float* out = (float*)d_out;

    int nbe = (N_EDGES + 255) / 256;         // 4883
    int gather_blocks = (N_NODES + 3) / 4;   // 25000

    // --- primary: counting-sort CSR ---
    // ws (ints): gcursor[512] | ovfcnt+pad[16] | ovf[2*OVF_CAP] |
    //            binbuf[NBINS*BCAP] | sorted[NBINS*BCAP] | offs[N_NODES] | len[N_NODES]
    {
        size_t need = (512 + 16 + 2 * (size_t)OVF_CAP +
                       2 * (size_t)NBINS * BCAP + 2 * (size_t)N_NODES) * sizeof(int);
        if (ws_size >= need) {
            int* gcursor = (int*)d_ws;
            int* ovfcnt  = gcursor + 512;
            int* ovf     = ovfcnt + 16;
            int* binbuf  = ovf + 2 * OVF_CAP;
            int* sorted  = binbuf + (size_t)NBINS * BCAP;
            int* offs    = sorted + (size_t)NBINS * BCAP;
            int* len     = offs + N_NODES;

            hipMemsetAsync(gcursor, 0, (512 + 16) * sizeof(int), stream);
            k1_bin_kernel<<<K1B, 512, 0, stream>>>(idxi, idxj, gcursor, ovfcnt, ovf, binbuf);
            k2_sort_kernel<<<NBINS, 1024, 0, stream>>>(gcursor, binbuf, sorted, offs, len);
            k3_gather_kernel<<<gather_blocks, 256, 0, stream>>>(x, offs, len, sorted, out);
            ovf_fixup_kernel<<<64, 256, 0, stream>>>(x, ovfcnt, ovf, out);
            return;
        }
    }

    // --- fallback #1: round-3 padded buckets ---
    {
        size_t need = ((size_t)N_NODES + 16 + 2 * (size_t)OVF_CAP +
                       (size_t)N_NODES * CAP) * sizeof(int);
        if (ws_size >= need) {
            int* cnt    = (int*)d_ws;
            int* ovfcnt = cnt + N_NODES;
            int* ovf    = cnt + N_NODES + 16;
            int* bucket = ovf + 2 * OVF_CAP;

            hipMemsetAsync(cnt, 0, (N_NODES + 16) * sizeof(int), stream);
            scatter_pad_kernel<<<nbe, 256, 0, stream>>>(idxi, idxj, cnt, ovfcnt, ovf, bucket);
            gather_pad_kernel<<<gather_blocks, 256, 0, stream>>>(x, cnt, bucket, out);
            ovf_fixup_kernel<<<64, 256, 0, stream>>>(x, ovfcnt, ovf, out);
            return;
        }
    }

    // --- fallback #2: atomic scatter-add ---
    int n4 = (N_NODES * D_FEAT) / 4;
    zero_f4_kernel<<<(n4 + 255) / 256, 256, 0, stream>>>(out, n4);
    long long total_threads = (long long)N_EDGES * 16;
    scatter_add_kernel<<<(int)((total_threads + 255) / 256), 256, 0, stream>>>(x, idxi, idxj, out);
}

// Round 8
// 147.668 us; speedup vs baseline: 4.8993x; 1.0152x over previous
//
#include <hip/hip_runtime.h>

#define N_NODES 100000
#define N_EDGES 1250000
#define D_FEAT  64

#define NPB     256                          // nodes per bin
#define NBINS   ((N_NODES + NPB - 1) / NPB)  // 391
#define BCAP    4096                         // entries per bin (mean 3196, +16 sigma)
#define EPB     4096                         // edges per k1 block
#define K1B     ((N_EDGES + EPB - 1) / EPB)  // 306
#define OVF_CAP 32768

#define CAP     48                           // fallback #1 per-node bucket cap

// =============== primary: LDS-staged counting sort + CSR gather ===============

// Coarse binning with LDS staging: block-local counting sort by bin, then
// run-coalesced dense writes (consecutive threads in a bin-run -> consecutive
// global addresses). Kills the 64-lanes-to-64-bins scattered-write pattern.
__global__ __launch_bounds__(512) void k1_bin_kernel(
        const int* __restrict__ idxi, const int* __restrict__ idxj,
        int* __restrict__ gcursor, int* __restrict__ ovfcnt,
        int* __restrict__ ovf, int* __restrict__ binbuf) {
    __shared__ int hist[512];                 // bins 0..390, padded for scan
    __shared__ int runstart[512];
    __shared__ int gbase[NBINS];
    __shared__ int cur[NBINS];
    __shared__ int staged[EPB];               // 16 KB
    __shared__ unsigned short sbin[EPB];      // 8 KB
    int t = threadIdx.x;
    hist[t] = 0;
    __syncthreads();

    long long base = (long long)blockIdx.x * EPB;
    int d[8], s[8], bn[8];
#pragma unroll
    for (int j = 0; j < 8; ++j) {
        long long e = base + t + j * 512;
        if (e < N_EDGES) {
            d[j] = idxi[e];
            s[j] = idxj[e];
            bn[j] = d[j] >> 8;
            atomicAdd(&hist[bn[j]], 1);
        } else {
            bn[j] = -1;
        }
    }
    __syncthreads();

    // inclusive scan of hist -> runstart, then make exclusive
    runstart[t] = hist[t];
    __syncthreads();
    for (int off = 1; off < 512; off <<= 1) {
        int add = (t >= off) ? runstart[t - off] : 0;
        __syncthreads();
        runstart[t] += add;
        __syncthreads();
    }
    int excl = runstart[t] - hist[t];
    __syncthreads();
    runstart[t] = excl;
    if (t < NBINS) {
        gbase[t] = hist[t] ? atomicAdd(&gcursor[t], hist[t]) : 0;
        cur[t] = 0;
    }
    __syncthreads();

    // stage entries ordered by bin
#pragma unroll
    for (int j = 0; j < 8; ++j) {
        if (bn[j] >= 0) {
            int lofs = atomicAdd(&cur[bn[j]], 1);
            int idx = runstart[bn[j]] + lofs;
            staged[idx] = ((d[j] & 255) << 17) | s[j];
            sbin[idx] = (unsigned short)bn[j];
        }
    }
    __syncthreads();

    // dense run-coalesced writes
    long long rem = (long long)N_EDGES - base;
    int n = (rem < EPB) ? (int)rem : EPB;
    for (int i = t; i < n; i += 512) {
        int b = sbin[i];
        int p = staged[i];
        int tgt = gbase[b] + (i - runstart[b]);
        if (tgt < BCAP) {
            binbuf[(size_t)b * BCAP + tgt] = p;
        } else {
            int op = atomicAdd(ovfcnt, 1);
            if (op < OVF_CAP) { ovf[2 * op] = b * NPB + (p >> 17); ovf[2 * op + 1] = p & 0x1FFFF; }
        }
    }
}

// Per-bin counting sort by local node id -> per-node CSR lists + offs/len.
__global__ __launch_bounds__(1024) void k2_sort_kernel(
        const int* __restrict__ gcursor, const int* __restrict__ binbuf,
        int* __restrict__ sorted, int* __restrict__ offs, int* __restrict__ len) {
    __shared__ int cnt[NPB];
    __shared__ int excl[NPB];
    __shared__ int cur[NPB];
    __shared__ int stmp[NPB];
    int bin = blockIdx.x;
    int t = threadIdx.x;
    if (t < NPB) cnt[t] = 0;
    __syncthreads();

    int n = gcursor[bin];
    if (n > BCAP) n = BCAP;
    const int* src = binbuf + (size_t)bin * BCAP;
    int p[4];
#pragma unroll
    for (int j = 0; j < 4; ++j) {
        int i = t + j * 1024;
        p[j] = (i < n) ? src[i] : -1;
        if (p[j] >= 0) atomicAdd(&cnt[p[j] >> 17], 1);
    }
    __syncthreads();

    // exclusive scan of cnt[256]
    if (t < NPB) stmp[t] = cnt[t];
    __syncthreads();
    for (int off = 1; off < NPB; off <<= 1) {
        int v = 0;
        if (t < NPB && t >= off) v = stmp[t - off];
        __syncthreads();
        if (t < NPB) stmp[t] += v;
        __syncthreads();
    }
    if (t < NPB) {
        excl[t] = stmp[t] - cnt[t];
        cur[t] = 0;
        int node = bin * NPB + t;
        if (node < N_NODES) {
            offs[node] = bin * BCAP + excl[t];
            len[node]  = cnt[t];
        }
    }
    __syncthreads();

    int* dst = sorted + (size_t)bin * BCAP;
#pragma unroll
    for (int j = 0; j < 4; ++j) {
        if (p[j] >= 0) {
            int dl = p[j] >> 17;
            int pos = excl[dl] + atomicAdd(&cur[dl], 1);
            dst[pos] = p[j] & 0x1FFFF;
        }
    }
}

// One wave per node; lanes = 4 sub-rows x 16 float4-columns. Each float4 load
// instruction covers 4 rows (1KB/wave); 2x unroll -> 8 rows in flight.
__global__ __launch_bounds__(256) void k3_gather_kernel(
        const float* __restrict__ x, const int* __restrict__ offs,
        const int* __restrict__ len, const int* __restrict__ sorted,
        float* __restrict__ out) {
    int node = blockIdx.x * 4 + (threadIdx.x >> 6);
    int lane = threadIdx.x & 63;
    if (node >= N_NODES) return;
    const int* b = sorted + offs[node];
    int l = len[node];
    int sub = lane >> 4;          // which row within a group of 4
    int c4  = lane & 15;          // which float4 column

    float4 acc = make_float4(0.f, 0.f, 0.f, 0.f);
    int k = 0;
    for (; k + 8 <= l; k += 8) {
        int s0 = b[k + sub];
        int s1 = b[k + 4 + sub];
        const float4 v0 = *(const float4*)(x + (size_t)s0 * D_FEAT + c4 * 4);
        const float4 v1 = *(const float4*)(x + (size_t)s1 * D_FEAT + c4 * 4);
        acc.x += v0.x + v1.x;
        acc.y += v0.y + v1.y;
        acc.z += v0.z + v1.z;
        acc.w += v0.w + v1.w;
    }
    if (k + 4 <= l) {
        int s0 = b[k + sub];
        const float4 v0 = *(const float4*)(x + (size_t)s0 * D_FEAT + c4 * 4);
        acc.x += v0.x; acc.y += v0.y; acc.z += v0.z; acc.w += v0.w;
        k += 4;
    }
    if (k + sub < l) {
        int s0 = b[k + sub];
        const float4 v0 = *(const float4*)(x + (size_t)s0 * D_FEAT + c4 * 4);
        acc.x += v0.x; acc.y += v0.y; acc.z += v0.z; acc.w += v0.w;
    }

    // fold the 4 sub-row partials (lanes differing in bits 4,5 share c4)
    acc.x += __shfl_xor(acc.x, 16, 64);
    acc.y += __shfl_xor(acc.y, 16, 64);
    acc.z += __shfl_xor(acc.z, 16, 64);
    acc.w += __shfl_xor(acc.w, 16, 64);
    acc.x += __shfl_xor(acc.x, 32, 64);
    acc.y += __shfl_xor(acc.y, 32, 64);
    acc.z += __shfl_xor(acc.z, 32, 64);
    acc.w += __shfl_xor(acc.w, 32, 64);

    if (lane < 16) {
        ((float4*)out)[(size_t)node * 16 + c4] = acc;
    }
}

// Add any overflow edges (statistically none) on top of the gathered output.
__global__ __launch_bounds__(256) void ovf_fixup_kernel(
        const float* __restrict__ x, const int* __restrict__ ovfcnt,
        const int* __restrict__ ovf, float* __restrict__ out) {
    int n = *ovfcnt;
    if (n > OVF_CAP) n = OVF_CAP;
    long long total = (long long)n * 16;
    long long stride = (long long)gridDim.x * blockDim.x;
    for (long long t = blockIdx.x * blockDim.x + threadIdx.x; t < total; t += stride) {
        int e  = (int)(t >> 4);
        int fo = ((int)t & 15) << 2;
        int d = ovf[2 * e];
        int s = ovf[2 * e + 1];
        const float4 v = *(const float4*)(x + (size_t)s * D_FEAT + fo);
        float* o = out + (size_t)d * D_FEAT + fo;
        atomicAdd(o + 0, v.x);
        atomicAdd(o + 1, v.y);
        atomicAdd(o + 2, v.z);
        atomicAdd(o + 3, v.w);
    }
}

// ====================== fallback #1: round-3 padded buckets ======================

__global__ __launch_bounds__(256) void scatter_pad_kernel(
        const int* __restrict__ idxi, const int* __restrict__ idxj,
        int* __restrict__ cnt, int* __restrict__ ovfcnt,
        int* __restrict__ ovf, int* __restrict__ bucket) {
    int e = blockIdx.x * blockDim.x + threadIdx.x;
    if (e >= N_EDGES) return;
    int d = idxi[e];
    int s = idxj[e];
    int pos = atomicAdd(&cnt[d], 1);
    if (pos < CAP) {
        bucket[(size_t)d * CAP + pos] = s;
    } else {
        int op = atomicAdd(ovfcnt, 1);
        if (op < OVF_CAP) { ovf[2 * op] = d; ovf[2 * op + 1] = s; }
    }
}

__global__ __launch_bounds__(256) void gather_pad_kernel(
        const float* __restrict__ x, const int* __restrict__ cnt,
        const int* __restrict__ bucket, float* __restrict__ out) {
    int node = blockIdx.x * 4 + (threadIdx.x >> 6);
    int lane = threadIdx.x & 63;
    if (node >= N_NODES) return;
    int c = cnt[node];
    if (c > CAP) c = CAP;
    const int* b = bucket + (size_t)node * CAP;
    float acc = 0.f;
    int k = 0;
    for (; k + 4 <= c; k += 4) {
        int4 s4 = *(const int4*)(b + k);
        float a0 = x[(size_t)s4.x * D_FEAT + lane];
        float a1 = x[(size_t)s4.y * D_FEAT + lane];
        float a2 = x[(size_t)s4.z * D_FEAT + lane];
        float a3 = x[(size_t)s4.w * D_FEAT + lane];
        acc += (a0 + a1) + (a2 + a3);
    }
    for (; k < c; ++k) acc += x[(size_t)b[k] * D_FEAT + lane];
    out[(size_t)node * D_FEAT + lane] = acc;
}

// ====================== fallback #2: atomic scatter-add ======================

__global__ __launch_bounds__(256) void zero_f4_kernel(float* __restrict__ out, int n4) {
    int i = blockIdx.x * blockDim.x + threadIdx.x;
    if (i < n4) ((float4*)out)[i] = make_float4(0.f, 0.f, 0.f, 0.f);
}

__global__ __launch_bounds__(256) void scatter_add_kernel(const float* __restrict__ x,
                                                          const int* __restrict__ idxi,
                                                          const int* __restrict__ idxj,
                                                          float* __restrict__ out) {
    int t = blockIdx.x * blockDim.x + threadIdx.x;
    int e = t >> 4;
    if (e >= N_EDGES) return;
    int fo = (t & 15) << 2;
    int dst = idxi[e];
    int src = idxj[e];
    const float4 v = *(const float4*)(x + (size_t)src * D_FEAT + fo);
    float* o = out + (size_t)dst * D_FEAT + fo;
    atomicAdd(o + 0, v.x);
    atomicAdd(o + 1, v.y);
    atomicAdd(o + 2, v.z);
    atomicAdd(o + 3, v.w);
}

extern "C" void kernel_launch(void* const* d_in, const int* in_sizes, int n_in,
                              void* d_out, int out_size, void* d_ws, size_t ws_size,
                              hipStream_t stream) {
    const float* x  = (const float*)d_in[0];
    const int*   ei = (const int*)d_in[1];   // flat (2, N_EDGES)
    const int*   idxi = ei;                  // row 0: destinations
    const int*   idxj = ei + N_EDGES;        // row 1: sources
    float* out = (float*)d_out;

    int nbe = (N_EDGES + 255) / 256;         // 4883
    int gather_blocks = (N_NODES + 3) / 4;   // 25000

    // --- primary: counting-sort CSR ---
    // ws (ints): gcursor[512] | ovfcnt+pad[16] | ovf[2*OVF_CAP] |
    //            binbuf[NBINS*BCAP] | sorted[NBINS*BCAP] | offs[N_NODES] | len[N_NODES]
    {
        size_t need = (512 + 16 + 2 * (size_t)OVF_CAP +
                       2 * (size_t)NBINS * BCAP + 2 * (size_t)N_NODES) * sizeof(int);
        if (ws_size >= need) {
            int* gcursor = (int*)d_ws;
            int* ovfcnt  = gcursor + 512;
            int* ovf     = ovfcnt + 16;
            int* binbuf  = ovf + 2 * OVF_CAP;
            int* sorted  = binbuf + (size_t)NBINS * BCAP;
            int* offs    = sorted + (size_t)NBINS * BCAP;
            int* len     = offs + N_NODES;

            hipMemsetAsync(gcursor, 0, (512 + 16) * sizeof(int), stream);
            k1_bin_kernel<<<K1B, 512, 0, stream>>>(idxi, idxj, gcursor, ovfcnt, ovf, binbuf);
            k2_sort_kernel<<<NBINS, 1024, 0, stream>>>(gcursor, binbuf, sorted, offs, len);
            k3_gather_kernel<<<gather_blocks, 256, 0, stream>>>(x, offs, len, sorted, out);
            ovf_fixup_kernel<<<64, 256, 0, stream>>>(x, ovfcnt, ovf, out);
            return;
        }
    }

    // --- fallback #1: round-3 padded buckets ---
    {
        size_t need = ((size_t)N_NODES + 16 + 2 * (size_t)OVF_CAP +
                       (size_t)N_NODES * CAP) * sizeof(int);
        if (ws_size >= need) {
            int* cnt    = (int*)d_ws;
            int* ovfcnt = cnt + N_NODES;
            int* ovf    = cnt + N_NODES + 16;
            int* bucket = ovf + 2 * OVF_CAP;

            hipMemsetAsync(cnt, 0, (N_NODES + 16) * sizeof(int), stream);
            scatter_pad_kernel<<<nbe, 256, 0, stream>>>(idxi, idxj, cnt, ovfcnt, ovf, bucket);
            gather_pad_kernel<<<gather_blocks, 256, 0, stream>>>(x, cnt, bucket, out);
            ovf_fixup_kernel<<<64, 256, 0, stream>>>(x, ovfcnt, ovf, out);
            return;
        }
    }

    // --- fallback #2: atomic scatter-add ---
    int n4 = (N_NODES * D_FEAT) / 4;
    zero_f4_kernel<<<(n4 + 255) / 256, 256, 0, stream>>>(out, n4);
    long long total_threads = (long long)N_EDGES * 16;
    scatter_add_kernel<<<(int)((total_threads + 255) / 256), 256, 0, stream>>>(x, idxi, idxj, out);
}

// Round 9
// 140.794 us; speedup vs baseline: 5.1385x; 1.0488x over previous
//
#include <hip/hip_runtime.h>

#define N_NODES 100000
#define N_EDGES 1250000
#define D_FEAT  64

#define NPB     256                          // nodes per bin
#define NBINS   ((N_NODES + NPB - 1) / NPB)  // 391
#define BCAP    4096                         // entries per bin (mean 3196, +16 sigma)
#define EPB     4096                         // edges per k1 block
#define K1B     ((N_EDGES + EPB - 1) / EPB)  // 306
#define OVF_CAP 32768

#define CAP     48                           // fallback #1 per-node bucket cap

// =============== primary: LDS-staged binning + fused sort/gather ===============

// Coarse binning with LDS staging: block-local counting sort by bin, then
// run-coalesced dense writes of packed (dloc<<17 | src) into per-bin regions.
__global__ __launch_bounds__(512) void k1_bin_kernel(
        const int* __restrict__ idxi, const int* __restrict__ idxj,
        int* __restrict__ gcursor, int* __restrict__ ovfcnt,
        int* __restrict__ ovf, int* __restrict__ binbuf) {
    __shared__ int hist[512];                 // bins 0..390, padded for scan
    __shared__ int runstart[512];
    __shared__ int gbase[NBINS];
    __shared__ int cur[NBINS];
    __shared__ int staged[EPB];               // 16 KB
    __shared__ unsigned short sbin[EPB];      // 8 KB
    int t = threadIdx.x;
    hist[t] = 0;
    __syncthreads();

    long long base = (long long)blockIdx.x * EPB;
    int d[8], s[8], bn[8];
#pragma unroll
    for (int j = 0; j < 8; ++j) {
        long long e = base + t + j * 512;
        if (e < N_EDGES) {
            d[j] = idxi[e];
            s[j] = idxj[e];
            bn[j] = d[j] >> 8;
            atomicAdd(&hist[bn[j]], 1);
        } else {
            bn[j] = -1;
        }
    }
    __syncthreads();

    runstart[t] = hist[t];
    __syncthreads();
    for (int off = 1; off < 512; off <<= 1) {
        int add = (t >= off) ? runstart[t - off] : 0;
        __syncthreads();
        runstart[t] += add;
        __syncthreads();
    }
    int excl = runstart[t] - hist[t];
    __syncthreads();
    runstart[t] = excl;
    if (t < NBINS) {
        gbase[t] = hist[t] ? atomicAdd(&gcursor[t], hist[t]) : 0;
        cur[t] = 0;
    }
    __syncthreads();

#pragma unroll
    for (int j = 0; j < 8; ++j) {
        if (bn[j] >= 0) {
            int lofs = atomicAdd(&cur[bn[j]], 1);
            int idx = runstart[bn[j]] + lofs;
            staged[idx] = ((d[j] & 255) << 17) | s[j];
            sbin[idx] = (unsigned short)bn[j];
        }
    }
    __syncthreads();

    long long rem = (long long)N_EDGES - base;
    int n = (rem < EPB) ? (int)rem : EPB;
    for (int i = t; i < n; i += 512) {
        int b = sbin[i];
        int p = staged[i];
        int tgt = gbase[b] + (i - runstart[b]);
        if (tgt < BCAP) {
            binbuf[(size_t)b * BCAP + tgt] = p;
        } else {
            int op = atomicAdd(ovfcnt, 1);
            if (op < OVF_CAP) { ovf[2 * op] = b * NPB + (p >> 17); ovf[2 * op + 1] = p & 0x1FFFF; }
        }
    }
}

// Fused: per-bin counting sort into a 16KB LDS list, then gather straight
// from LDS. One block per bin, 16 waves; wave w gathers nodes w*16..w*16+15.
__global__ __launch_bounds__(1024) void k23_fused_kernel(
        const float* __restrict__ x, const int* __restrict__ gcursor,
        const int* __restrict__ binbuf, float* __restrict__ out) {
    __shared__ int cnt[NPB];
    __shared__ int excl[NPB];
    __shared__ int cur[NPB];
    __shared__ int stmp[NPB];
    __shared__ int srt[BCAP];                 // 16 KB sorted source list
    int bin = blockIdx.x;
    int t = threadIdx.x;
    if (t < NPB) cnt[t] = 0;
    __syncthreads();

    int n = gcursor[bin];
    if (n > BCAP) n = BCAP;
    const int* src = binbuf + (size_t)bin * BCAP;
    int p[4];
#pragma unroll
    for (int j = 0; j < 4; ++j) {
        int i = t + j * 1024;
        p[j] = (i < n) ? src[i] : -1;
        if (p[j] >= 0) atomicAdd(&cnt[p[j] >> 17], 1);
    }
    __syncthreads();

    // exclusive scan of cnt[256]
    if (t < NPB) stmp[t] = cnt[t];
    __syncthreads();
    for (int off = 1; off < NPB; off <<= 1) {
        int v = 0;
        if (t < NPB && t >= off) v = stmp[t - off];
        __syncthreads();
        if (t < NPB) stmp[t] += v;
        __syncthreads();
    }
    if (t < NPB) {
        excl[t] = stmp[t] - cnt[t];
        cur[t] = 0;
    }
    __syncthreads();

#pragma unroll
    for (int j = 0; j < 4; ++j) {
        if (p[j] >= 0) {
            int dl = p[j] >> 17;
            int pos = excl[dl] + atomicAdd(&cur[dl], 1);
            srt[pos] = p[j] & 0x1FFFF;
        }
    }
    __syncthreads();

    // gather: wave w -> nodes w*16 .. w*16+15, sub-row float4 layout
    int wave = t >> 6;
    int lane = t & 63;
    int sub  = lane >> 4;
    int c4   = lane & 15;
    for (int i = 0; i < 16; ++i) {
        int dloc = wave * 16 + i;
        int node = bin * NPB + dloc;
        if (node >= N_NODES) break;
        int base = excl[dloc];
        int l = cnt[dloc];
        float4 acc = make_float4(0.f, 0.f, 0.f, 0.f);
        int k = 0;
        for (; k + 8 <= l; k += 8) {
            int s0 = srt[base + k + sub];
            int s1 = srt[base + k + 4 + sub];
            const float4 v0 = *(const float4*)(x + (size_t)s0 * D_FEAT + c4 * 4);
            const float4 v1 = *(const float4*)(x + (size_t)s1 * D_FEAT + c4 * 4);
            acc.x += v0.x + v1.x;
            acc.y += v0.y + v1.y;
            acc.z += v0.z + v1.z;
            acc.w += v0.w + v1.w;
        }
        if (k + 4 <= l) {
            int s0 = srt[base + k + sub];
            const float4 v0 = *(const float4*)(x + (size_t)s0 * D_FEAT + c4 * 4);
            acc.x += v0.x; acc.y += v0.y; acc.z += v0.z; acc.w += v0.w;
            k += 4;
        }
        if (k + sub < l) {
            int s0 = srt[base + k + sub];
            const float4 v0 = *(const float4*)(x + (size_t)s0 * D_FEAT + c4 * 4);
            acc.x += v0.x; acc.y += v0.y; acc.z += v0.z; acc.w += v0.w;
        }

        acc.x += __shfl_xor(acc.x, 16, 64);
        acc.y += __shfl_xor(acc.y, 16, 64);
        acc.z += __shfl_xor(acc.z, 16, 64);
        acc.w += __shfl_xor(acc.w, 16, 64);
        acc.x += __shfl_xor(acc.x, 32, 64);
        acc.y += __shfl_xor(acc.y, 32, 64);
        acc.z += __shfl_xor(acc.z, 32, 64);
        acc.w += __shfl_xor(acc.w, 32, 64);

        if (lane < 16) {
            ((float4*)out)[(size_t)node * 16 + c4] = acc;
        }
    }
}

// Add any overflow edges (statistically none) on top of the gathered output.
__global__ __launch_bounds__(256) void ovf_fixup_kernel(
        const float* __restrict__ x, const int* __restrict__ ovfcnt,
        const int* __restrict__ ovf, float* __restrict__ out) {
    int n = *ovfcnt;
    if (n > OVF_CAP) n = OVF_CAP;
    long long total = (long long)n * 16;
    long long stride = (long long)gridDim.x * blockDim.x;
    for (long long t = blockIdx.x * blockDim.x + threadIdx.x; t < total; t += stride) {
        int e  = (int)(t >> 4);
        int fo = ((int)t & 15) << 2;
        int d = ovf[2 * e];
        int s = ovf[2 * e + 1];
        const float4 v = *(const float4*)(x + (size_t)s * D_FEAT + fo);
        float* o = out + (size_t)d * D_FEAT + fo;
        atomicAdd(o + 0, v.x);
        atomicAdd(o + 1, v.y);
        atomicAdd(o + 2, v.z);
        atomicAdd(o + 3, v.w);
    }
}

// ====================== fallback #1: round-3 padded buckets ======================

__global__ __launch_bounds__(256) void scatter_pad_kernel(
        const int* __restrict__ idxi, const int* __restrict__ idxj,
        int* __restrict__ cnt, int* __restrict__ ovfcnt,
        int* __restrict__ ovf, int* __restrict__ bucket) {
    int e = blockIdx.x * blockDim.x + threadIdx.x;
    if (e >= N_EDGES) return;
    int d = idxi[e];
    int s = idxj[e];
    int pos = atomicAdd(&cnt[d], 1);
    if (pos < CAP) {
        bucket[(size_t)d * CAP + pos] = s;
    } else {
        int op = atomicAdd(ovfcnt, 1);
        if (op < OVF_CAP) { ovf[2 * op] = d; ovf[2 * op + 1] = s; }
    }
}

__global__ __launch_bounds__(256) void gather_pad_kernel(
        const float* __restrict__ x, const int* __restrict__ cnt,
        const int* __restrict__ bucket, float* __restrict__ out) {
    int node = blockIdx.x * 4 + (threadIdx.x >> 6);
    int lane = threadIdx.x & 63;
    if (node >= N_NODES) return;
    int c = cnt[node];
    if (c > CAP) c = CAP;
    const int* b = bucket + (size_t)node * CAP;
    float acc = 0.f;
    int k = 0;
    for (; k + 4 <= c; k += 4) {
        int4 s4 = *(const int4*)(b + k);
        float a0 = x[(size_t)s4.x * D_FEAT + lane];
        float a1 = x[(size_t)s4.y * D_FEAT + lane];
        float a2 = x[(size_t)s4.z * D_FEAT + lane];
        float a3 = x[(size_t)s4.w * D_FEAT + lane];
        acc += (a0 + a1) + (a2 + a3);
    }
    for (; k < c; ++k) acc += x[(size_t)b[k] * D_FEAT + lane];
    out[(size_t)node * D_FEAT + lane] = acc;
}

// ====================== fallback #2: atomic scatter-add ======================

__global__ __launch_bounds__(256) void zero_f4_kernel(float* __restrict__ out, int n4) {
    int i = blockIdx.x * blockDim.x + threadIdx.x;
    if (i < n4) ((float4*)out)[i] = make_float4(0.f, 0.f, 0.f, 0.f);
}

__global__ __launch_bounds__(256) void scatter_add_kernel(const float* __restrict__ x,
                                                          const int* __restrict__ idxi,
                                                          const int* __restrict__ idxj,
                                                          float* __restrict__ out) {
    int t = blockIdx.x * blockDim.x + threadIdx.x;
    int e = t >> 4;
    if (e >= N_EDGES) return;
    int fo = (t & 15) << 2;
    int dst = idxi[e];
    int src = idxj[e];
    const float4 v = *(const float4*)(x + (size_t)src * D_FEAT + fo);
    float* o = out + (size_t)dst * D_FEAT + fo;
    atomicAdd(o + 0, v.x);
    atomicAdd(o + 1, v.y);
    atomicAdd(o + 2, v.z);
    atomicAdd(o + 3, v.w);
}

extern "C" void kernel_launch(void* const* d_in, const int* in_sizes, int n_in,
                              void* d_out, int out_size, void* d_ws, size_t ws_size,
                              hipStream_t stream) {
    const float* x  = (const float*)d_in[0];
    const int*   ei = (const int*)d_in[1];   // flat (2, N_EDGES)
    const int*   idxi = ei;                  // row 0: destinations
    const int*   idxj = ei + N_EDGES;        // row 1: sources
    float* out = (float*)d_out;

    int nbe = (N_EDGES + 255) / 256;         // 4883
    int gather_blocks = (N_NODES + 3) / 4;   // 25000

    // --- primary: counting-sort + fused sort/gather ---
    // ws (ints): gcursor[512] | ovfcnt+pad[16] | ovf[2*OVF_CAP] | binbuf[NBINS*BCAP]
    {
        size_t need = (512 + 16 + 2 * (size_t)OVF_CAP +
                       (size_t)NBINS * BCAP) * sizeof(int);
        if (ws_size >= need) {
            int* gcursor = (int*)d_ws;
            int* ovfcnt  = gcursor + 512;
            int* ovf     = ovfcnt + 16;
            int* binbuf  = ovf + 2 * OVF_CAP;

            hipMemsetAsync(gcursor, 0, (512 + 16) * sizeof(int), stream);
            k1_bin_kernel<<<K1B, 512, 0, stream>>>(idxi, idxj, gcursor, ovfcnt, ovf, binbuf);
            k23_fused_kernel<<<NBINS, 1024, 0, stream>>>(x, gcursor, binbuf, out);
            ovf_fixup_kernel<<<16, 256, 0, stream>>>(x, ovfcnt, ovf, out);
            return;
        }
    }

    // --- fallback #1: round-3 padded buckets ---
    {
        size_t need = ((size_t)N_NODES + 16 + 2 * (size_t)OVF_CAP +
                       (size_t)N_NODES * CAP) * sizeof(int);
        if (ws_size >= need) {
            int* cnt    = (int*)d_ws;
            int* ovfcnt = cnt + N_NODES;
            int* ovf    = cnt + N_NODES + 16;
            int* bucket = ovf + 2 * OVF_CAP;

            hipMemsetAsync(cnt, 0, (N_NODES + 16) * sizeof(int), stream);
            scatter_pad_kernel<<<nbe, 256, 0, stream>>>(idxi, idxj, cnt, ovfcnt, ovf, bucket);
            gather_pad_kernel<<<gather_blocks, 256, 0, stream>>>(x, cnt, bucket, out);
            ovf_fixup_kernel<<<16, 256, 0, stream>>>(x, ovfcnt, ovf, out);
            return;
        }
    }

    // --- fallback #2: atomic scatter-add ---
    int n4 = (N_NODES * D_FEAT) / 4;
    zero_f4_kernel<<<(n4 + 255) / 256, 256, 0, stream>>>(out, n4);
    long long total_threads = (long long)N_EDGES * 16;
    scatter_add_kernel<<<(int)((total_threads + 255) / 256), 256, 0, stream>>>(x, idxi, idxj, out);
}